// Round 18
// baseline (169.263 us; speedup 1.0000x reference)
//
#include <hip/hip_runtime.h>
#include <stdint.h>

using bf16   = __bf16;
using bf16x4 = __attribute__((ext_vector_type(4))) __bf16;
using bf16x8 = __attribute__((ext_vector_type(8))) __bf16;
using f32x4  = __attribute__((ext_vector_type(4))) float;

#define DEPTH   11
#define NTREES  16
#define DM      256
#define PER     4095      // 2^12 - 1 nodes per tree
#define KDIM    512       // 2*DM
#define NGATES  5

__device__ __forceinline__ float sigf(float x) { return 1.0f / (1.0f + __expf(-x)); }
__device__ __forceinline__ float tanh_fast(float x) {
    float e = __expf(2.0f * x);
    return 1.0f - 2.0f / (e + 1.0f);   // safe at +/-inf
}

__device__ __forceinline__ void load_lds16(const bf16* g, bf16* l) {
    __builtin_amdgcn_global_load_lds((const __attribute__((address_space(1))) void*)g,
                                     (__attribute__((address_space(3))) void*)l,
                                     16, 0, 0);
}

// Fused setup kernel.
// Blocks [0,320): Wfrag repack (MFMA-fragment order, for level_big/splitk).
// Blocks [320,480): Wt transpose (plain [1280][512] bf16, for level_8p B-staging).
// Blocks [480,8672): leaf embedding.
__global__ __launch_bounds__(256) void setup_kernel(
        const float* __restrict__ W, bf16* __restrict__ Wf, bf16* __restrict__ Wt,
        const int* __restrict__ tokens, const float* __restrict__ emb,
        float* acts, bf16* actsb) {
    int bid = blockIdx.x;
    if (bid < 320) {
        int tid = bid * 256 + threadIdx.x;          // 0 .. 81919
        int f   = tid >> 6;                         // fragment id 0..1279
        int l   = tid & 63;
        int gt  = f >> 4;
        int ks  = f & 15;
        int n   = (gt << 4) + (l & 15);
        int k0  = (ks << 5) + ((l >> 4) << 3);
        bf16x8 v;
        #pragma unroll
        for (int e = 0; e < 8; ++e) v[e] = (bf16)W[(size_t)(k0 + e) * 1280 + n];
        *reinterpret_cast<bf16x8*>(Wf + (size_t)tid * 8) = v;
        return;
    }
    if (bid < 480) {
        // 64x64 LDS transpose tiles: 8 k-tiles x 20 n-tiles
        __shared__ float tile[64][65];
        int t  = threadIdx.x;
        int bb = bid - 320;
        int kt = bb / 20;
        int nt = bb - kt * 20;
        int kk0 = kt << 6, n0 = nt << 6;
        int rr = t >> 6;
        int cc = t & 63;
        #pragma unroll
        for (int i = 0; i < 16; ++i) {
            int kl = (rr << 4) + i;
            tile[kl][cc] = W[(size_t)(kk0 + kl) * 1280 + n0 + cc];
        }
        __syncthreads();
        #pragma unroll
        for (int i = 0; i < 16; ++i) {
            int nl = (rr << 4) + i;
            Wt[(size_t)(n0 + nl) * KDIM + kk0 + cc] = (bf16)tile[cc][nl];
        }
        return;
    }
    int wid  = ((bid - 480) * 256 + threadIdx.x) >> 6;  // leaf index 0..32767
    int lane = threadIdx.x & 63;
    int b    = wid >> 11;
    int loc  = wid & 2047;
    int id   = b * PER + loc;
    int tok  = tokens[id];

    float4 e = *reinterpret_cast<const float4*>(emb + tok * DM + lane * 4);
    float ss = e.x * e.x + e.y * e.y + e.z * e.z + e.w * e.w;
    #pragma unroll
    for (int off = 32; off; off >>= 1) ss += __shfl_xor(ss, off);
    float scale = fminf(1.0f, 1.0f / fmaxf(sqrtf(ss), 1e-7f));
    e.x *= scale; e.y *= scale; e.z *= scale; e.w *= scale;

    int o = id * DM + lane * 4;
    *reinterpret_cast<float4*>(acts + o) = e;
    bf16x4 eb;
    eb.x = (bf16)e.x; eb.y = (bf16)e.y; eb.z = (bf16)e.z; eb.w = (bf16)e.w;
    *reinterpret_cast<bf16x4*>(actsb + o) = eb;
}

// ---------- Phase-interleaved kernel for levels 1-2 (Mt >= 512) ----------
// 512 thr / 8 waves. Tile: 128 rows x 64 ucols (x5 gates = 320 cols), BK=64.
// Wave w: rows (w>>2)*64..+64, ucols (w&3)*16..+16; acc[5][4].
// LDS (112 KB, 1 block/CU): A[2][8][128][8] linear (conflict-free per
// quarter-wave), B[2][320][8][8] with involution swizzle kb' = kb ^ (col&7)
// applied on BOTH the stage SOURCE address and the ds_read slot (rule #21:
// gload_lds dest stays linear).
// Per K-tile (BK=64 = TWO 32-k slices): issue all 7 stage lines for kt+1 at
// phase 0, {9 ds_read + 20 MFMA}, s_barrier, {9 ds_read + 20 MFMA},
// __syncthreads (vmcnt drain covered by ~40 MFMA/wave since issue).
__global__ __launch_bounds__(512, 1) void level_8p(
        const bf16* __restrict__ actsb_in, const bf16* __restrict__ Wt,
        const float* __restrict__ bias, float* __restrict__ mem,
        float* __restrict__ acts, bf16* __restrict__ actsb_out,
        int off_k, int off_km1, int zmem) {
    __shared__ __align__(16) bf16 ldsA[2][8][128][8];      // 32 KB
    __shared__ __align__(16) bf16 ldsB[2][320][8][8];      // 80 KB

    int t    = threadIdx.x;
    int lane = t & 63;
    int w    = t >> 6;
    int lo   = lane & 15;
    int hi   = lane >> 4;          // 0..3
    int rw   = w >> 2;             // 0..1 : 64-row group
    int uw   = w & 3;              // 0..3 : 16-ucol slot

    int rt  = blockIdx.x >> 2;     // 128-row tile within tree
    int uct = blockIdx.x & 3;      // 64-ucol tile
    int b   = blockIdx.y;          // tree
    int rm  = rt << 7;
    int uc0 = uct << 6;

    const bf16* Abase = actsb_in + (size_t)(b * PER + off_km1) * DM;

    // A stage: slot s = i*512+t -> kb = s>>7, row = s&127 (linear dest)
    const bf16* aSrc[2];
    #pragma unroll
    for (int i = 0; i < 2; ++i) {
        int s   = i * 512 + t;
        aSrc[i] = Abase + (size_t)(rm + (s & 127)) * KDIM + (s >> 7) * 8;
    }
    // B stage: slot s = j*512+t -> col = s>>3, kb' = s&7; true kb = kb'^(col&7).
    const bf16* bSrc[5];
    #pragma unroll
    for (int j = 0; j < 5; ++j) {
        int s   = j * 512 + t;
        int cc  = s >> 3;                       // 0..319
        int kb  = (s & 7) ^ (cc & 7);
        int n   = (cc >> 6) * DM + uc0 + (cc & 63);
        bSrc[j] = Wt + (size_t)n * KDIM + kb * 8;
    }

    int ucol = uc0 + (uw << 4) + lo;
    float bi[NGATES];
    #pragma unroll
    for (int g = 0; g < NGATES; ++g) bi[g] = bias[g * DM + ucol];

    // prologue: stage K-tile 0 into buf 0
    #pragma unroll
    for (int i = 0; i < 2; ++i)
        load_lds16(aSrc[i], &ldsA[0][0][0][0] + (i * 512 + t) * 8);
    #pragma unroll
    for (int j = 0; j < 5; ++j)
        load_lds16(bSrc[j], &ldsB[0][0][0][0] + (j * 512 + t) * 8);

    f32x4 acc[NGATES][4] = {};

    __syncthreads();

    for (int kt = 0; kt < 8; ++kt) {
        int cur = kt & 1;
        bf16* dstA = &ldsA[cur ^ 1][0][0][0];
        bf16* dstB = &ldsB[cur ^ 1][0][0][0];
        int ko = (kt + 1) * 64;

        #pragma unroll
        for (int kq = 0; kq < 2; ++kq) {       // BK=64 -> two 32-k slices
            if (kt < 7 && kq == 0) {           // front-load all 7 stage issues
                load_lds16(aSrc[0] + ko, dstA + t * 8);
                load_lds16(aSrc[1] + ko, dstA + (512 + t) * 8);
                #pragma unroll
                for (int j = 0; j < 5; ++j)
                    load_lds16(bSrc[j] + ko, dstB + (j * 512 + t) * 8);
            }

            bf16x8 bb[NGATES];
            #pragma unroll
            for (int g = 0; g < NGATES; ++g) {
                int cc  = (g << 6) + (uw << 4) + lo;
                int kbp = ((kq << 2) + hi) ^ (cc & 7);   // in [0,8)
                bb[g] = *reinterpret_cast<const bf16x8*>(&ldsB[cur][cc][kbp][0]);
            }
            #pragma unroll
            for (int rg = 0; rg < 4; ++rg) {
                bf16x8 af = *reinterpret_cast<const bf16x8*>(
                    &ldsA[cur][(kq << 2) + hi][(rw << 6) + (rg << 4) + lo][0]);
                #pragma unroll
                for (int g = 0; g < NGATES; ++g)
                    acc[g][rg] = __builtin_amdgcn_mfma_f32_16x16x32_bf16(af, bb[g], acc[g][rg], 0, 0, 0);
            }
            if (kq == 0) __builtin_amdgcn_s_barrier();   // phase barrier (no drain)
        }
        __syncthreads();   // tile barrier: drains stages (covered by ~40 MFMA)
    }

    int treebase = b * PER;
    #pragma unroll
    for (int rg = 0; rg < 4; ++rg) {
        #pragma unroll
        for (int r = 0; r < 4; ++r) {
            int ml = rm + (rw << 6) + (rg << 4) + (hi << 2) + r;
            int id = treebase + off_k + ml;
            float cl = 0.0f, cr = 0.0f;
            if (!zmem) {
                int ch = (treebase + off_km1 + (ml << 1)) * DM + ucol;
                cl = mem[ch];
                cr = mem[ch + DM];
            }
            float gi = acc[0][rg][r] + bi[0];
            float gl = acc[1][rg][r] + bi[1];
            float gr = acc[2][rg][r] + bi[2];
            float go = acc[3][rg][r] + bi[3];
            float gu = acc[4][rg][r] + bi[4];
            float c  = sigf(gi) * tanh_fast(gu) + sigf(gl) * cl + sigf(gr) * cr;
            float h  = sigf(go) * tanh_fast(c);
            int oi = id * DM + ucol;
            acts[oi]      = h;
            mem[oi]       = c;
            actsb_out[oi] = (bf16)h;
        }
    }
}

// ---------- Big-level kernel (levels 3-4): R13-verified structure ----------
__global__ __launch_bounds__(256, 2) void level_big(
        const bf16* __restrict__ actsb_in, const bf16* __restrict__ Wfrag,
        const float* __restrict__ bias, float* __restrict__ mem,
        float* __restrict__ acts, bf16* __restrict__ actsb_out,
        int off_k, int off_km1, int zmem) {
    constexpr int RPB = 64;
    constexpr int NRG = 4;
    constexpr int NLD = 4;
    __shared__ __align__(16) bf16 ldsA[2][16][RPB][8];

    int t    = threadIdx.x;
    int lane = t & 63;
    int w    = t >> 6;
    int lo   = lane & 15;
    int hi   = lane >> 4;

    int rt    = blockIdx.x >> 2;
    int uct   = blockIdx.x & 3;
    int b     = blockIdx.y;
    int rm    = rt * RPB;
    int wslot = (uct << 2) + w;

    const bf16* Abase = actsb_in + (size_t)(b * PER + off_km1) * DM;

    const bf16* aSrc[NLD];
    #pragma unroll
    for (int i = 0; i < NLD; ++i) {
        int s   = i * 256 + t;
        aSrc[i] = Abase + (size_t)(rm + (s & (RPB - 1))) * KDIM + (s / RPB) * 8;
    }

    const bf16* bbase = Wfrag + ((size_t)wslot << 13) + lane * 8;

    int ucol = (wslot << 4) + lo;
    float bi[NGATES];
    #pragma unroll
    for (int g = 0; g < NGATES; ++g) bi[g] = bias[g * DM + ucol];

    #pragma unroll
    for (int i = 0; i < NLD; ++i)
        load_lds16(aSrc[i], &ldsA[0][0][0][0] + (i * 256 + t) * 8);

    f32x4 acc[NGATES][NRG] = {};

    __syncthreads();

    for (int kt = 0; kt < 4; ++kt) {
        int cur = kt & 1;
        if (kt < 3) {
            int ko = (kt + 1) * 128;
            #pragma unroll
            for (int i = 0; i < NLD; ++i)
                load_lds16(aSrc[i] + ko, &ldsA[cur ^ 1][0][0][0] + (i * 256 + t) * 8);
        }

        #pragma unroll
        for (int kq = 0; kq < 4; ++kq) {
            bf16x8 bb[NGATES];
            #pragma unroll
            for (int g = 0; g < NGATES; ++g)
                bb[g] = *reinterpret_cast<const bf16x8*>(bbase + (size_t)(((g << 8) | ((kt << 2) + kq)) << 9));
            #pragma unroll
            for (int rg = 0; rg < NRG; ++rg) {
                bf16x8 af = *reinterpret_cast<const bf16x8*>(&ldsA[cur][(kq << 2) + hi][(rg << 4) + lo][0]);
                #pragma unroll
                for (int g = 0; g < NGATES; ++g)
                    acc[g][rg] = __builtin_amdgcn_mfma_f32_16x16x32_bf16(af, bb[g], acc[g][rg], 0, 0, 0);
            }
        }
        __syncthreads();
    }

    int treebase = b * PER;
    #pragma unroll
    for (int rg = 0; rg < NRG; ++rg) {
        #pragma unroll
        for (int r = 0; r < 4; ++r) {
            int ml = rm + (rg << 4) + (hi << 2) + r;
            int id = treebase + off_k + ml;
            float cl = 0.0f, cr = 0.0f;
            if (!zmem) {
                int ch = (treebase + off_km1 + (ml << 1)) * DM + ucol;
                cl = mem[ch];
                cr = mem[ch + DM];
            }
            float gi = acc[0][rg][r] + bi[0];
            float gl = acc[1][rg][r] + bi[1];
            float gr = acc[2][rg][r] + bi[2];
            float go = acc[3][rg][r] + bi[3];
            float gu = acc[4][rg][r] + bi[4];
            float c  = sigf(gi) * tanh_fast(gu) + sigf(gl) * cl + sigf(gr) * cr;
            float h  = sigf(go) * tanh_fast(c);
            int oi = id * DM + ucol;
            acts[oi]      = h;
            mem[oi]       = c;
            actsb_out[oi] = (bf16)h;
        }
    }
}

// ---------- Split-K tail kernel (Mt < 128): 8-way K-split, 512 thr ----------
__global__ __launch_bounds__(512) void level_splitk(
        const bf16* __restrict__ actsb_in, const bf16* __restrict__ Wfrag,
        const float* __restrict__ bias, float* mem, float* acts, bf16* actsb_out,
        int off_k, int off_km1, int shift) {
    __shared__ f32x4 red[7][NGATES][64];

    int t    = threadIdx.x;
    int lane = t & 63;
    int w    = t >> 6;
    int lo   = lane & 15;
    int hi   = lane >> 4;
    int tile = blockIdx.x >> 4;
    int uc   = blockIdx.x & 15;
    int m0   = tile << 4;
    int mask = (1 << shift) - 1;

    int mA   = m0 + lo;
    int rowA = (mA >> shift) * PER + off_km1 + ((mA & mask) << 1);
    const bf16* aptr  = actsb_in + (size_t)rowA * DM + hi * 8 + (w << 1) * 32;
    const bf16* bbase = Wfrag + ((size_t)uc << 13) + lane * 8;

    f32x4 acc[NGATES] = {};
    #pragma unroll
    for (int kk = 0; kk < 2; ++kk) {
        int kt = (w << 1) + kk;
        bf16x8 a = *reinterpret_cast<const bf16x8*>(aptr + kk * 32);
        #pragma unroll
        for (int g = 0; g < NGATES; ++g) {
            bf16x8 bb = *reinterpret_cast<const bf16x8*>(bbase + (size_t)(((g << 8) + kt) << 9));
            acc[g] = __builtin_amdgcn_mfma_f32_16x16x32_bf16(a, bb, acc[g], 0, 0, 0);
        }
    }

    if (w) {
        #pragma unroll
        for (int g = 0; g < NGATES; ++g) red[w - 1][g][lane] = acc[g];
    }
    __syncthreads();
    if (w == 0) {
        int ucol = (uc << 4) + lo;
        float bi[NGATES];
        #pragma unroll
        for (int g = 0; g < NGATES; ++g) {
            #pragma unroll
            for (int p = 0; p < 7; ++p) acc[g] += red[p][g][lane];
            bi[g] = bias[g * DM + ucol];
        }
        #pragma unroll
        for (int r = 0; r < 4; ++r) {
            int m   = m0 + (hi << 2) + r;
            int tb  = (m >> shift) * PER;
            int loc = m & mask;
            int id  = tb + off_k + loc;
            int ch  = (tb + off_km1 + (loc << 1)) * DM + ucol;
            float cl = mem[ch];
            float cr = mem[ch + DM];
            float gi = acc[0][r] + bi[0];
            float gl = acc[1][r] + bi[1];
            float gr = acc[2][r] + bi[2];
            float go = acc[3][r] + bi[3];
            float gu = acc[4][r] + bi[4];
            float c  = sigf(gi) * tanh_fast(gu) + sigf(gl) * cl + sigf(gr) * cr;
            float h  = sigf(go) * tanh_fast(c);
            int oi = id * DM + ucol;
            acts[oi]      = h;
            mem[oi]       = c;
            actsb_out[oi] = (bf16)h;
        }
    }
}

extern "C" void kernel_launch(void* const* d_in, const int* in_sizes, int n_in,
                              void* d_out, int out_size, void* d_ws, size_t ws_size,
                              hipStream_t stream) {
    (void)in_sizes; (void)n_in; (void)out_size; (void)ws_size;
    const int*   tokens = (const int*)d_in[0];
    const float* emb    = (const float*)d_in[8];
    const float* W      = (const float*)d_in[9];
    const float* bias   = (const float*)d_in[10];
    float* acts = (float*)d_out;

    char* ws = (char*)d_ws;
    bf16*  Wfrag = (bf16*)ws;                               // 1,310,720 B
    bf16*  Wt    = (bf16*)(ws + 1310720);                   // 1,310,720 B
    bf16*  actsb = (bf16*)(ws + 2621440);                   // 33,546,240 B
    float* mem   = (float*)(ws + 2621440 + 33546240);       // 67,092,480 B

    setup_kernel<<<dim3(480 + 8192), dim3(256), 0, stream>>>(
        W, Wfrag, Wt, tokens, emb, acts, actsb);

    int off_km1 = 0;
    for (int k = 1; k <= DEPTH; ++k) {
        int shift   = DEPTH - k;
        int Mt      = 1 << shift;            // rows per tree at this level
        int off_k   = off_km1 + (Mt << 1);
        int M_total = NTREES << shift;
        if (Mt >= 512) {
            // levels 1-2: phase-interleaved, 128-row x 64-ucol tiles
            level_8p<<<dim3((Mt >> 7) * 4, NTREES), dim3(512), 0, stream>>>(
                actsb, Wt, bias, mem, acts, actsb, off_k, off_km1, (k == 1) ? 1 : 0);
        } else if (Mt >= 128) {
            level_big<<<dim3((Mt / 64) * 4, NTREES), dim3(256), 0, stream>>>(
                actsb, Wfrag, bias, mem, acts, actsb, off_k, off_km1, 0);
        } else {
            level_splitk<<<dim3(M_total), dim3(512), 0, stream>>>(
                actsb, Wfrag, bias, mem, acts, actsb, off_k, off_km1, shift);
        }
        off_km1 = off_k;
    }
}